// Round 1
// baseline (246.485 us; speedup 1.0000x reference)
//
#include <hip/hip_runtime.h>

#define T_TOK 12544   // 4*56*56
#define EMB   256
#define HEADS 8
#define HD    32
#define IMG   56
#define SCALE 0.17677669529663689f

typedef unsigned int u32;

__device__ __forceinline__ u32 bf16_rtne(float f) {
    u32 u = __builtin_bit_cast(u32, f);
    return (u + 0x7fffu + ((u >> 16) & 1u)) >> 16;
}
__device__ __forceinline__ u32 pack_bf2(float lo, float hi) {
    return bf16_rtne(lo) | (bf16_rtne(hi) << 16);
}
__device__ __forceinline__ float bf_lo(u32 u) { return __builtin_bit_cast(float, u << 16); }
__device__ __forceinline__ float bf_hi(u32 u) { return __builtin_bit_cast(float, u & 0xffff0000u); }

// ---------------------------------------------------------------------------
// Shared 128x128 fp32 GEMM core: C[128][128] = A[128][256] * B[128][256]^T
// A rows = tokens, B rows = output channels (both read along K, row-major).
// LDS stored transposed [k][col] with XOR swizzle on the float4-group index
// so compute reads are aligned ds_read_b128 with <=2-way bank conflicts.
// Thread (tx,ty): rows 8*ty..8*ty+7, cols {4*tx..+3} and {64+4*tx..+3}.
// ---------------------------------------------------------------------------
__device__ __forceinline__ void gemm_core(const float* __restrict__ aBase,
                                          const float* __restrict__ bBase,
                                          float* As, float* Bs,
                                          float acc[8][8]) {
    const int tid = threadIdx.x;
    const int c4 = tid & 7;       // k-quad within 32-wide K tile
    const int r  = tid >> 3;      // 0..31
    const int tx = tid & 15, ty = tid >> 4;

    for (int kt = 0; kt < 8; ++kt) {
        const int k0 = kt * 32;
        #pragma unroll
        for (int i = 0; i < 4; ++i) {
            const int row = r + i * 32;
            const float4 av = *(const float4*)&aBase[(size_t)row * EMB + k0 + c4 * 4];
            const float4 wv = *(const float4*)&bBase[(size_t)row * EMB + k0 + c4 * 4];
            const int col = ((((row >> 2) ^ c4) << 2) | (row & 3));
            As[(c4 * 4 + 0) * 128 + col] = av.x;
            As[(c4 * 4 + 1) * 128 + col] = av.y;
            As[(c4 * 4 + 2) * 128 + col] = av.z;
            As[(c4 * 4 + 3) * 128 + col] = av.w;
            Bs[(c4 * 4 + 0) * 128 + col] = wv.x;
            Bs[(c4 * 4 + 1) * 128 + col] = wv.y;
            Bs[(c4 * 4 + 2) * 128 + col] = wv.z;
            Bs[(c4 * 4 + 3) * 128 + col] = wv.w;
        }
        __syncthreads();
        #pragma unroll
        for (int kk = 0; kk < 32; ++kk) {
            const int kq = kk >> 2;
            const float4 a0 = *(const float4*)&As[kk * 128 + (((2 * ty) ^ kq) << 2)];
            const float4 a1 = *(const float4*)&As[kk * 128 + (((2 * ty + 1) ^ kq) << 2)];
            const float4 b0 = *(const float4*)&Bs[kk * 128 + ((tx ^ kq) << 2)];
            const float4 b1 = *(const float4*)&Bs[kk * 128 + (((tx + 16) ^ kq) << 2)];
            const float a[8] = {a0.x, a0.y, a0.z, a0.w, a1.x, a1.y, a1.z, a1.w};
            const float b[8] = {b0.x, b0.y, b0.z, b0.w, b1.x, b1.y, b1.z, b1.w};
            #pragma unroll
            for (int i = 0; i < 8; ++i)
                #pragma unroll
                for (int j = 0; j < 8; ++j)
                    acc[i][j] += a[i] * b[j];
        }
        __syncthreads();
    }
}

// Fused QKV: grid (98, 6). nTile>>1 selects q/k/v; q stored fp32 [T][256],
// k/v stored as packed bf16 pairs [T][128] (halves attention LDS+global traffic).
__global__ __launch_bounds__(256, 3) void qkv_gemm(
    const float* __restrict__ x,
    const float* __restrict__ wq, const float* __restrict__ wk, const float* __restrict__ wv,
    const float* __restrict__ bq, const float* __restrict__ bk, const float* __restrict__ bv,
    float* __restrict__ qo, u32* __restrict__ kp, u32* __restrict__ vp) {
    __shared__ __attribute__((aligned(16))) float As[32 * 128];
    __shared__ __attribute__((aligned(16))) float Bs[32 * 128];

    const int mBase = blockIdx.x * 128;
    const int nTile = blockIdx.y;
    const int which = nTile >> 1;
    const int colBase = (nTile & 1) * 128;
    const float* w    = (which == 0) ? wq : (which == 1) ? wk : wv;
    const float* bias = (which == 0) ? bq : (which == 1) ? bk : bv;

    float acc[8][8] = {};
    gemm_core(x + (size_t)mBase * EMB, w + (size_t)colBase * EMB, As, Bs, acc);

    const int tx = threadIdx.x & 15, ty = threadIdx.x >> 4;
    float bz[8];
    #pragma unroll
    for (int j = 0; j < 4; ++j) {
        bz[j]     = bias[colBase + 4 * tx + j];
        bz[j + 4] = bias[colBase + 64 + 4 * tx + j];
    }

    if (which == 0) {
        #pragma unroll
        for (int i = 0; i < 8; ++i) {
            const size_t row = mBase + 8 * ty + i;
            float4 s0 = {acc[i][0] + bz[0], acc[i][1] + bz[1], acc[i][2] + bz[2], acc[i][3] + bz[3]};
            float4 s1 = {acc[i][4] + bz[4], acc[i][5] + bz[5], acc[i][6] + bz[6], acc[i][7] + bz[7]};
            *(float4*)&qo[row * EMB + colBase + 4 * tx] = s0;
            *(float4*)&qo[row * EMB + colBase + 64 + 4 * tx] = s1;
        }
    } else {
        u32* dst = (which == 1) ? kp : vp;
        #pragma unroll
        for (int i = 0; i < 8; ++i) {
            const size_t row = mBase + 8 * ty + i;
            float v0 = acc[i][0] + bz[0], v1 = acc[i][1] + bz[1];
            float v2 = acc[i][2] + bz[2], v3 = acc[i][3] + bz[3];
            float v4 = acc[i][4] + bz[4], v5 = acc[i][5] + bz[5];
            float v6 = acc[i][6] + bz[6], v7 = acc[i][7] + bz[7];
            uint2 p0 = {pack_bf2(v0, v1), pack_bf2(v2, v3)};
            uint2 p1 = {pack_bf2(v4, v5), pack_bf2(v6, v7)};
            *(uint2*)&dst[row * 128 + (colBase >> 1) + 2 * tx] = p0;
            *(uint2*)&dst[row * 128 + (colBase >> 1) + 32 + 2 * tx] = p1;
        }
    }
}

// Attention: grid (7,7,32), 64 threads = one 8x8 pixel tile, one (image,head).
// Halo 14x14 of k/v staged in LDS as packed bf16 pairs, dim-major [16][196]
// (lanes index by pixel -> near-conflict-free b32 reads). OOB halo is
// zero-filled => logit 0 exactly, matching F.unfold zero padding semantics.
__global__ __launch_bounds__(64) void attn_kernel(
    const float* __restrict__ q, const u32* __restrict__ kp, const u32* __restrict__ vp,
    float* __restrict__ ao) {
    __shared__ u32 kT[16 * 196];
    __shared__ u32 vT[16 * 196];

    const int bImg = blockIdx.z >> 3, h = blockIdx.z & 7;
    const int ty0 = blockIdx.y * 8, tx0 = blockIdx.x * 8;
    const int tid = threadIdx.x;

    for (int p = tid; p < 196; p += 64) {
        const int pyh = p / 14, pxh = p % 14;
        const int gy = ty0 - 3 + pyh, gx = tx0 - 3 + pxh;
        if ((unsigned)gy < 56u && (unsigned)gx < 56u) {
            const size_t t = ((size_t)bImg * IMG + gy) * IMG + gx;
            const uint4* ksrc = (const uint4*)&kp[t * 128 + h * 16];
            const uint4* vsrc = (const uint4*)&vp[t * 128 + h * 16];
            #pragma unroll
            for (int q4 = 0; q4 < 4; ++q4) {
                uint4 ku = ksrc[q4];
                kT[(q4 * 4 + 0) * 196 + p] = ku.x;
                kT[(q4 * 4 + 1) * 196 + p] = ku.y;
                kT[(q4 * 4 + 2) * 196 + p] = ku.z;
                kT[(q4 * 4 + 3) * 196 + p] = ku.w;
                uint4 vu = vsrc[q4];
                vT[(q4 * 4 + 0) * 196 + p] = vu.x;
                vT[(q4 * 4 + 1) * 196 + p] = vu.y;
                vT[(q4 * 4 + 2) * 196 + p] = vu.z;
                vT[(q4 * 4 + 3) * 196 + p] = vu.w;
            }
        } else {
            #pragma unroll
            for (int d = 0; d < 16; ++d) { kT[d * 196 + p] = 0u; vT[d * 196 + p] = 0u; }
        }
    }
    __syncthreads();

    const int py = tid >> 3, px = tid & 7;
    const size_t t = ((size_t)bImg * IMG + ty0 + py) * IMG + tx0 + px;

    float qr[32];
    const float4* qsrc = (const float4*)&q[t * EMB + h * HD];
    #pragma unroll
    for (int i = 0; i < 8; ++i) {
        float4 f = qsrc[i];
        qr[4 * i] = f.x; qr[4 * i + 1] = f.y; qr[4 * i + 2] = f.z; qr[4 * i + 3] = f.w;
    }

    float lg[49];
    #pragma unroll
    for (int jy = 0; jy < 7; ++jy) {
        #pragma unroll
        for (int jx = 0; jx < 7; ++jx) {
            const int p = (py + jy) * 14 + (px + jx);
            float acc = 0.f;
            #pragma unroll
            for (int i = 0; i < 16; ++i) {
                const u32 u = kT[i * 196 + p];
                acc += qr[2 * i] * bf_lo(u);
                acc += qr[2 * i + 1] * bf_hi(u);
            }
            lg[jy * 7 + jx] = acc * SCALE;
        }
    }

    float m = lg[0];
    #pragma unroll
    for (int j = 1; j < 49; ++j) m = fmaxf(m, lg[j]);
    float s = 0.f;
    #pragma unroll
    for (int j = 0; j < 49; ++j) { lg[j] = __expf(lg[j] - m); s += lg[j]; }
    const float inv = 1.0f / s;

    float o[32] = {};
    #pragma unroll
    for (int jy = 0; jy < 7; ++jy) {
        #pragma unroll
        for (int jx = 0; jx < 7; ++jx) {
            const int p = (py + jy) * 14 + (px + jx);
            const float wgt = lg[jy * 7 + jx];
            #pragma unroll
            for (int i = 0; i < 16; ++i) {
                const u32 u = vT[i * 196 + p];
                o[2 * i] += wgt * bf_lo(u);
                o[2 * i + 1] += wgt * bf_hi(u);
            }
        }
    }

    float* dst = &ao[t * EMB + h * HD];
    #pragma unroll
    for (int i = 0; i < 8; ++i) {
        float4 f = {o[4 * i] * inv, o[4 * i + 1] * inv, o[4 * i + 2] * inv, o[4 * i + 3] * inv};
        *(float4*)&dst[4 * i] = f;
    }
}

// Output projection: grid (98, 2). out = ao @ wo^T + bo, fp32 to d_out.
__global__ __launch_bounds__(256, 3) void out_gemm(
    const float* __restrict__ ao, const float* __restrict__ wo,
    const float* __restrict__ bo, float* __restrict__ out) {
    __shared__ __attribute__((aligned(16))) float As[32 * 128];
    __shared__ __attribute__((aligned(16))) float Bs[32 * 128];

    const int mBase = blockIdx.x * 128;
    const int nBase = blockIdx.y * 128;

    float acc[8][8] = {};
    gemm_core(ao + (size_t)mBase * EMB, wo + (size_t)nBase * EMB, As, Bs, acc);

    const int tx = threadIdx.x & 15, ty = threadIdx.x >> 4;
    float bz[8];
    #pragma unroll
    for (int j = 0; j < 4; ++j) {
        bz[j]     = bo[nBase + 4 * tx + j];
        bz[j + 4] = bo[nBase + 64 + 4 * tx + j];
    }
    #pragma unroll
    for (int i = 0; i < 8; ++i) {
        const size_t row = mBase + 8 * ty + i;
        float4 s0 = {acc[i][0] + bz[0], acc[i][1] + bz[1], acc[i][2] + bz[2], acc[i][3] + bz[3]};
        float4 s1 = {acc[i][4] + bz[4], acc[i][5] + bz[5], acc[i][6] + bz[6], acc[i][7] + bz[7]};
        *(float4*)&out[row * EMB + nBase + 4 * tx] = s0;
        *(float4*)&out[row * EMB + nBase + 64 + 4 * tx] = s1;
    }
}

extern "C" void kernel_launch(void* const* d_in, const int* in_sizes, int n_in,
                              void* d_out, int out_size, void* d_ws, size_t ws_size,
                              hipStream_t stream) {
    const float* x  = (const float*)d_in[0];
    const float* wq = (const float*)d_in[1];
    const float* wk = (const float*)d_in[2];
    const float* wv = (const float*)d_in[3];
    const float* wo = (const float*)d_in[4];
    const float* bq = (const float*)d_in[5];
    const float* bk = (const float*)d_in[6];
    const float* bv = (const float*)d_in[7];
    const float* bo = (const float*)d_in[8];
    float* out = (float*)d_out;

    // workspace: q fp32 [T][256] | k bf16x2 [T][128] | v bf16x2 [T][128] | ao fp32 [T][256]
    float* qbuf = (float*)d_ws;
    u32* kpk = (u32*)(qbuf + (size_t)T_TOK * EMB);
    u32* vpk = kpk + (size_t)T_TOK * 128;
    float* ao = (float*)(vpk + (size_t)T_TOK * 128);

    qkv_gemm<<<dim3(98, 6), 256, 0, stream>>>(x, wq, wk, wv, bq, bk, bv, qbuf, kpk, vpk);
    attn_kernel<<<dim3(7, 7, 32), 64, 0, stream>>>(qbuf, kpk, vpk, ao);
    out_gemm<<<dim3(98, 2), 256, 0, stream>>>(ao, wo, bo, out);
}

// Round 2
// 180.484 us; speedup vs baseline: 1.3657x; 1.3657x over previous
//
#include <hip/hip_runtime.h>

typedef unsigned int u32;
typedef unsigned short u16;
typedef __attribute__((ext_vector_type(8))) short bf16x8;
typedef __attribute__((ext_vector_type(4))) float f32x4;

#define T_TOK 12544   // 4*56*56
#define EMB   256
#define IMG   56
#define SCALE 0.17677669529663689f

__device__ __forceinline__ u32 bf16_rtne(float f) {
    u32 u = __builtin_bit_cast(u32, f);
    return (u + 0x7fffu + ((u >> 16) & 1u)) >> 16;
}
__device__ __forceinline__ float bf16_to_f(u32 h) { return __builtin_bit_cast(float, h << 16); }
__device__ __forceinline__ float bf_lo(u32 u) { return __builtin_bit_cast(float, u << 16); }
__device__ __forceinline__ float bf_hi(u32 u) { return __builtin_bit_cast(float, u & 0xffff0000u); }

// async global->LDS, 16B per lane; LDS dest is wave-uniform base + lane*16
#define GLD16(g, l) __builtin_amdgcn_global_load_lds( \
    (const __attribute__((address_space(1))) u32*)(g), \
    (__attribute__((address_space(3))) u32*)(l), 16, 0, 0)

// ---------------------------------------------------------------------------
// Split fp32 -> bf16 hi/lo pairs: x (12544x256) and the 4 weight matrices.
// qkv weights land stacked [768][256] (wq rows 0-255, wk 256-511, wv 512-767).
// ---------------------------------------------------------------------------
__global__ __launch_bounds__(256) void convert_kernel(
    const float* __restrict__ x, const float* __restrict__ wq, const float* __restrict__ wk,
    const float* __restrict__ wv, const float* __restrict__ wo,
    u16* __restrict__ xh, u16* __restrict__ xl,
    u16* __restrict__ bsh, u16* __restrict__ bsl,
    u16* __restrict__ boh, u16* __restrict__ bol) {
    const int i = blockIdx.x * 256 + threadIdx.x;
    const int NX4 = T_TOK * EMB / 4;   // 802816 float4s
    float4 f;
    u16 *dh, *dl;
    int di;
    if (i < NX4) {
        f = ((const float4*)x)[i];
        dh = xh; dl = xl; di = i;
    } else {
        const int j = i - NX4;                 // < 65536
        const int w = j >> 14, widx = j & 16383;
        const float* src = (w == 0) ? wq : (w == 1) ? wk : (w == 2) ? wv : wo;
        f = ((const float4*)src)[widx];
        if (w < 3) { dh = bsh; dl = bsl; di = (w << 14) + widx; }
        else       { dh = boh; dl = bol; di = widx; }
    }
    const float vf[4] = {f.x, f.y, f.z, f.w};
    ushort4 hv, lv;
    u16* hp = (u16*)&hv; u16* lp = (u16*)&lv;
    #pragma unroll
    for (int c = 0; c < 4; ++c) {
        const u32 h = bf16_rtne(vf[c]);
        hp[c] = (u16)h;
        lp[c] = (u16)bf16_rtne(vf[c] - bf16_to_f(h));
    }
    ((ushort4*)dh)[di] = hv;
    ((ushort4*)dl)[di] = lv;
}

// ---------------------------------------------------------------------------
// m97-style MFMA main loop: C[128][128] += A[128x256] * B[128x256]^T with
// split-bf16 3-pass (Ah*Bh + Al*Bh + Ah*Bl). 256 thr = 4 waves, each 64x64.
// LDS tiles [128 rows][32 k] bf16, staged via global_load_lds width 16.
// ---------------------------------------------------------------------------
__device__ __forceinline__ void mfma_loop(
    const u16* __restrict__ Ah, const u16* __restrict__ Al,
    const u16* __restrict__ Bh, const u16* __restrict__ Bl,
    int mBase, int nBase, u16* sA, u16* sB, f32x4 acc[4][4]) {
    const int tid = threadIdx.x;
    const int wv = tid >> 6, ln = tid & 63;
    const int lrow = ln & 15, lqd = ln >> 4;
    const int wm = (wv & 1) * 64, wn = (wv >> 1) * 64;
    // staging chunk c -> row = c>>2, 16B k-chunk = c&3; wave w covers chunks [128w,128w+128)
    const int c0 = wv * 128 + ln, r0 = c0 >> 2, kc0 = c0 & 3;
    const int c1 = c0 + 64,       r1 = c1 >> 2, kc1 = c1 & 3;
    u16* ldsA0 = sA + (size_t)(wv * 128) * 8;
    u16* ldsA1 = sA + (size_t)(wv * 128 + 64) * 8;
    u16* ldsB0 = sB + (size_t)(wv * 128) * 8;
    u16* ldsB1 = sB + (size_t)(wv * 128 + 64) * 8;

    for (int it = 0; it < 24; ++it) {
        const int pa = it >> 3, kt = it & 7;
        const u16* A = (pa == 1) ? Al : Ah;
        const u16* B = (pa == 2) ? Bl : Bh;
        const int k0 = kt * 32;
        GLD16(A + (size_t)(mBase + r0) * EMB + k0 + kc0 * 8, ldsA0);
        GLD16(A + (size_t)(mBase + r1) * EMB + k0 + kc1 * 8, ldsA1);
        GLD16(B + (size_t)(nBase + r0) * EMB + k0 + kc0 * 8, ldsB0);
        GLD16(B + (size_t)(nBase + r1) * EMB + k0 + kc1 * 8, ldsB1);
        __syncthreads();
        bf16x8 af[4], bfr[4];
        #pragma unroll
        for (int mi = 0; mi < 4; ++mi)
            af[mi] = *(const bf16x8*)&sA[(wm + mi * 16 + lrow) * 32 + lqd * 8];
        #pragma unroll
        for (int ni = 0; ni < 4; ++ni)
            bfr[ni] = *(const bf16x8*)&sB[(wn + ni * 16 + lrow) * 32 + lqd * 8];
        #pragma unroll
        for (int mi = 0; mi < 4; ++mi)
            #pragma unroll
            for (int ni = 0; ni < 4; ++ni)
                acc[mi][ni] = __builtin_amdgcn_mfma_f32_16x16x32_bf16(af[mi], bfr[ni], acc[mi][ni], 0, 0, 0);
        __syncthreads();
    }
}

// QKV: grid (98,6). Cols 0-255 -> q fp32; 256-511 -> k bf16; 512-767 -> v bf16.
__global__ __launch_bounds__(256) void qkv_mfma(
    const u16* __restrict__ xh, const u16* __restrict__ xl,
    const u16* __restrict__ bsh, const u16* __restrict__ bsl,
    const float* __restrict__ bq, const float* __restrict__ bk, const float* __restrict__ bv,
    float* __restrict__ qf, u16* __restrict__ kb, u16* __restrict__ vb) {
    __shared__ __attribute__((aligned(16))) u16 sA[128 * 32];
    __shared__ __attribute__((aligned(16))) u16 sB[128 * 32];
    const int mBase = blockIdx.x * 128;
    const int nBase = blockIdx.y * 128;
    f32x4 acc[4][4];
    #pragma unroll
    for (int mi = 0; mi < 4; ++mi)
        #pragma unroll
        for (int ni = 0; ni < 4; ++ni)
            acc[mi][ni] = (f32x4){0.f, 0.f, 0.f, 0.f};

    mfma_loop(xh, xl, bsh, bsl, mBase, nBase, sA, sB, acc);

    const int tid = threadIdx.x;
    const int wv = tid >> 6, ln = tid & 63;
    const int lrow = ln & 15, lqd = ln >> 4;
    const int wm = (wv & 1) * 64, wn = (wv >> 1) * 64;
    const int which = nBase >> 8;   // uniform per block: 0=q, 1=k, 2=v
    const float* bias = (which == 0) ? bq : (which == 1) ? bk : bv;
    #pragma unroll
    for (int ni = 0; ni < 4; ++ni) {
        const int ncol = nBase + wn + ni * 16 + lrow;
        const int c = ncol & 255;
        const float bz = bias[c];
        #pragma unroll
        for (int mi = 0; mi < 4; ++mi) {
            #pragma unroll
            for (int r = 0; r < 4; ++r) {
                const int row = mBase + wm + mi * 16 + lqd * 4 + r;
                const float val = acc[mi][ni][r] + bz;
                if (which == 0)      qf[(size_t)row * EMB + c] = val;
                else if (which == 1) kb[(size_t)row * EMB + c] = (u16)bf16_rtne(val);
                else                 vb[(size_t)row * EMB + c] = (u16)bf16_rtne(val);
            }
        }
    }
}

// Out-projection: grid (98,2). Reads attn's split-bf16 output, writes fp32.
__global__ __launch_bounds__(256) void out_mfma(
    const u16* __restrict__ aoh, const u16* __restrict__ aol,
    const u16* __restrict__ boh, const u16* __restrict__ bol,
    const float* __restrict__ bo, float* __restrict__ out) {
    __shared__ __attribute__((aligned(16))) u16 sA[128 * 32];
    __shared__ __attribute__((aligned(16))) u16 sB[128 * 32];
    const int mBase = blockIdx.x * 128;
    const int nBase = blockIdx.y * 128;
    f32x4 acc[4][4];
    #pragma unroll
    for (int mi = 0; mi < 4; ++mi)
        #pragma unroll
        for (int ni = 0; ni < 4; ++ni)
            acc[mi][ni] = (f32x4){0.f, 0.f, 0.f, 0.f};

    mfma_loop(aoh, aol, boh, bol, mBase, nBase, sA, sB, acc);

    const int tid = threadIdx.x;
    const int wv = tid >> 6, ln = tid & 63;
    const int lrow = ln & 15, lqd = ln >> 4;
    const int wm = (wv & 1) * 64, wn = (wv >> 1) * 64;
    #pragma unroll
    for (int ni = 0; ni < 4; ++ni) {
        const int ncol = nBase + wn + ni * 16 + lrow;
        const float bz = bo[ncol];
        #pragma unroll
        for (int mi = 0; mi < 4; ++mi) {
            #pragma unroll
            for (int r = 0; r < 4; ++r) {
                const int row = mBase + wm + mi * 16 + lqd * 4 + r;
                out[(size_t)row * EMB + ncol] = acc[mi][ni][r] + bz;
            }
        }
    }
}

// ---------------------------------------------------------------------------
// Attention: 128 threads = 2 waves = 2 heads, 8x8 pixel tile. Halo 14x14 of
// k AND v staged as packed-bf16 u32, [head][k/v][dimpair 16][pixel 196].
// OOB halo zero-filled => logit 0, matching F.unfold zero padding.
// Output written as split-bf16 (hi/lo) feeding out_mfma directly.
// ---------------------------------------------------------------------------
__global__ __launch_bounds__(128) void attn_kernel(
    const float* __restrict__ q, const u16* __restrict__ kb, const u16* __restrict__ vb,
    u16* __restrict__ aoh, u16* __restrict__ aol) {
    __shared__ u32 sKV[2 * 2 * 16 * 196];   // 50176 B
    const int tid = threadIdx.x;
    const int img = blockIdx.z >> 2;
    const int hg  = (blockIdx.z & 3) * 2;
    const int ty0 = blockIdx.y * 8, tx0 = blockIdx.x * 8;

    for (int i = tid; i < 392; i += 128) {
        int hl = 0, p = i;
        if (p >= 196) { hl = 1; p -= 196; }
        const int gy = ty0 - 3 + p / 14;
        const int gx = tx0 - 3 + p % 14;
        u32* kd = &sKV[(hl * 2 + 0) * 16 * 196 + p];
        u32* vd = &sKV[(hl * 2 + 1) * 16 * 196 + p];
        if ((unsigned)gy < 56u && (unsigned)gx < 56u) {
            const size_t t = ((size_t)img * IMG + gy) * IMG + gx;
            const uint4* ks = (const uint4*)&kb[t * EMB + (hg + hl) * 32];
            const uint4* vs = (const uint4*)&vb[t * EMB + (hg + hl) * 32];
            #pragma unroll
            for (int c = 0; c < 4; ++c) {
                const uint4 ku = ks[c];
                kd[(c * 4 + 0) * 196] = ku.x; kd[(c * 4 + 1) * 196] = ku.y;
                kd[(c * 4 + 2) * 196] = ku.z; kd[(c * 4 + 3) * 196] = ku.w;
                const uint4 vu = vs[c];
                vd[(c * 4 + 0) * 196] = vu.x; vd[(c * 4 + 1) * 196] = vu.y;
                vd[(c * 4 + 2) * 196] = vu.z; vd[(c * 4 + 3) * 196] = vu.w;
            }
        } else {
            #pragma unroll
            for (int d = 0; d < 16; ++d) { kd[d * 196] = 0u; vd[d * 196] = 0u; }
        }
    }
    __syncthreads();

    const int hl = tid >> 6, ln = tid & 63;
    const int head = hg + hl;
    const int py = ln >> 3, px = ln & 7;
    const size_t t = ((size_t)img * IMG + ty0 + py) * IMG + tx0 + px;

    float qr[32];
    const float4* qs = (const float4*)&q[t * EMB + head * 32];
    #pragma unroll
    for (int i = 0; i < 8; ++i) {
        const float4 f = qs[i];
        qr[4*i] = f.x; qr[4*i+1] = f.y; qr[4*i+2] = f.z; qr[4*i+3] = f.w;
    }

    const u32* kBase = &sKV[(hl * 2 + 0) * 16 * 196];
    const u32* vBase = &sKV[(hl * 2 + 1) * 16 * 196];

    float lg[49];
    #pragma unroll
    for (int jy = 0; jy < 7; ++jy)
        #pragma unroll
        for (int jx = 0; jx < 7; ++jx) {
            const int p = (py + jy) * 14 + px + jx;
            float a0 = 0.f, a1 = 0.f;
            #pragma unroll
            for (int d = 0; d < 16; ++d) {
                const u32 u = kBase[d * 196 + p];
                a0 += qr[2*d]   * bf_lo(u);
                a1 += qr[2*d+1] * bf_hi(u);
            }
            lg[jy * 7 + jx] = (a0 + a1) * SCALE;
        }

    float m = lg[0];
    #pragma unroll
    for (int j = 1; j < 49; ++j) m = fmaxf(m, lg[j]);
    float s = 0.f;
    #pragma unroll
    for (int j = 0; j < 49; ++j) { lg[j] = __expf(lg[j] - m); s += lg[j]; }
    const float inv = 1.0f / s;

    float o[32] = {};
    #pragma unroll
    for (int jy = 0; jy < 7; ++jy)
        #pragma unroll
        for (int jx = 0; jx < 7; ++jx) {
            const int p = (py + jy) * 14 + px + jx;
            const float wgt = lg[jy * 7 + jx];
            #pragma unroll
            for (int d = 0; d < 16; ++d) {
                const u32 u = vBase[d * 196 + p];
                o[2*d]   += wgt * bf_lo(u);
                o[2*d+1] += wgt * bf_hi(u);
            }
        }

    u16* ohp = &aoh[t * EMB + head * 32];
    u16* olp = &aol[t * EMB + head * 32];
    #pragma unroll
    for (int g = 0; g < 8; ++g) {
        ushort4 hv, lv;
        u16* hp = (u16*)&hv; u16* lp = (u16*)&lv;
        #pragma unroll
        for (int c = 0; c < 4; ++c) {
            const float v = o[g * 4 + c] * inv;
            const u32 h = bf16_rtne(v);
            hp[c] = (u16)h;
            lp[c] = (u16)bf16_rtne(v - bf16_to_f(h));
        }
        ((ushort4*)ohp)[g] = hv;
        ((ushort4*)olp)[g] = lv;
    }
}

extern "C" void kernel_launch(void* const* d_in, const int* in_sizes, int n_in,
                              void* d_out, int out_size, void* d_ws, size_t ws_size,
                              hipStream_t stream) {
    const float* x  = (const float*)d_in[0];
    const float* wq = (const float*)d_in[1];
    const float* wk = (const float*)d_in[2];
    const float* wv = (const float*)d_in[3];
    const float* wo = (const float*)d_in[4];
    const float* bq = (const float*)d_in[5];
    const float* bk = (const float*)d_in[6];
    const float* bv = (const float*)d_in[7];
    const float* bo = (const float*)d_in[8];
    float* out = (float*)d_out;

    char* ws = (char*)d_ws;
    u16*   xh  = (u16*)(ws);                  // 6,422,528 B
    u16*   xl  = (u16*)(ws + 6422528);        // 6,422,528 B
    float* qf  = (float*)(ws + 12845056);     // 12,845,056 B
    u16*   kb  = (u16*)(ws + 25690112);       // 6,422,528 B
    u16*   vb  = (u16*)(ws + 32112640);       // 6,422,528 B
    u16*   bsh = (u16*)(ws + 38535168);       // 393,216 B (stacked qkv hi)
    u16*   bsl = (u16*)(ws + 38928384);       // 393,216 B
    u16*   boh = (u16*)(ws + 39321600);       // 131,072 B
    u16*   bol = (u16*)(ws + 39452672);       // 131,072 B -> total 39,583,744 B
    // xh/xl are dead after qkv_mfma; attn reuses them as its split-bf16 output
    u16* aoh = xh;
    u16* aol = xl;

    convert_kernel<<<3392, 256, 0, stream>>>(x, wq, wk, wv, wo, xh, xl, bsh, bsl, boh, bol);
    qkv_mfma<<<dim3(98, 6), 256, 0, stream>>>(xh, xl, bsh, bsl, bq, bk, bv, qf, kb, vb);
    attn_kernel<<<dim3(7, 7, 16), 128, 0, stream>>>(qf, kb, vb, aoh, aol);
    out_mfma<<<dim3(98, 2), 256, 0, stream>>>(aoh, aol, boh, bol, bo, out);
}